// Round 1
// baseline (313.491 us; speedup 1.0000x reference)
//
#include <hip/hip_runtime.h>

#define D_FEAT 32

__global__ void deg_kernel(const int* __restrict__ src, int* __restrict__ deg, int n_edges) {
    int e = blockIdx.x * blockDim.x + threadIdx.x;
    if (e < n_edges) atomicAdd(&deg[src[e]], 1);
}

__global__ void norm_kernel(const int* __restrict__ deg, float* __restrict__ norm, int n_nodes) {
    int i = blockIdx.x * blockDim.x + threadIdx.x;
    if (i < n_nodes) {
        int d = deg[i];
        norm[i] = d > 0 ? rsqrtf((float)d) : 0.0f;
    }
}

// 32 threads per edge: lane d handles feature dim d.
__global__ void scatter_kernel(const float* __restrict__ feat,
                               const int* __restrict__ src,
                               const int* __restrict__ dst,
                               const float* __restrict__ norm,
                               float* __restrict__ out, int n_edges) {
    int t = blockIdx.x * blockDim.x + threadIdx.x;
    int e = t >> 5;   // edge index
    int d = t & 31;   // feature dim
    if (e < n_edges) {
        int s  = src[e];
        int dd = dst[e];
        float v = feat[s * D_FEAT + d] * norm[s];
        atomicAdd(&out[dd * D_FEAT + d], v);
    }
}

// one thread per float4 (8 threads per node row)
__global__ void post_scale_kernel(float4* __restrict__ out4,
                                  const float* __restrict__ norm, int n4) {
    int t = blockIdx.x * blockDim.x + threadIdx.x;
    if (t < n4) {
        float nv = norm[t >> 3];  // 32 floats/node = 8 float4s/node
        float4 v = out4[t];
        v.x *= nv; v.y *= nv; v.z *= nv; v.w *= nv;
        out4[t] = v;
    }
}

extern "C" void kernel_launch(void* const* d_in, const int* in_sizes, int n_in,
                              void* d_out, int out_size, void* d_ws, size_t ws_size,
                              hipStream_t stream) {
    const float* feat = (const float*)d_in[0];
    const int*   src  = (const int*)d_in[1];
    const int*   dst  = (const int*)d_in[2];
    float* out = (float*)d_out;

    const int n_nodes = in_sizes[0] / D_FEAT;
    const int n_edges = in_sizes[1];

    // workspace layout: deg (int[n_nodes]) | norm (float[n_nodes])
    int*   deg  = (int*)d_ws;
    float* norm = (float*)((char*)d_ws + (((size_t)n_nodes * sizeof(int) + 255) & ~(size_t)255));

    hipMemsetAsync(deg, 0, (size_t)n_nodes * sizeof(int), stream);
    hipMemsetAsync(d_out, 0, (size_t)out_size * sizeof(float), stream);

    const int B = 256;
    deg_kernel<<<(n_edges + B - 1) / B, B, 0, stream>>>(src, deg, n_edges);
    norm_kernel<<<(n_nodes + B - 1) / B, B, 0, stream>>>(deg, norm, n_nodes);

    long long total = (long long)n_edges * 32;
    int grid = (int)((total + B - 1) / B);
    scatter_kernel<<<grid, B, 0, stream>>>(feat, src, dst, norm, out, n_edges);

    int n4 = out_size / 4;
    post_scale_kernel<<<(n4 + B - 1) / B, B, 0, stream>>>((float4*)out, norm, n4);
}